// Round 2
// baseline (1411.280 us; speedup 1.0000x reference)
//
#include <hip/hip_runtime.h>
#include <hip/hip_bf16.h>

typedef unsigned short ushortT;
typedef __attribute__((ext_vector_type(8))) short short8;
typedef __attribute__((ext_vector_type(4))) float f32x4;

#define MFMA16(a,b,c) __builtin_amdgcn_mfma_f32_16x16x32_bf16(a,b,c,0,0,0)

__device__ __forceinline__ ushortT f2bf(float f){
  union {float f; unsigned u;} v; v.f = f;
  unsigned r = v.u + 0x7FFFu + ((v.u >> 16) & 1u);
  return (ushortT)(r >> 16);
}
__device__ __forceinline__ float bf2f(ushortT u){
  union {unsigned u; float f;} v; v.u = ((unsigned)u) << 16; return v.f;
}

// B=64, C=192, IMG=56, WS=7, SS=3, NH=6, DH=32, N=49, nWs=8, windows=4096, T=200704
#define SCALE_Q 0.17677669529663687f

// ---------------- k_prep: weight permute/convert + bias/mask table ----------------
__global__ void k_prep(const float* __restrict__ rpb, const float* __restrict__ wqkv,
                       const float* __restrict__ bqkv, const float* __restrict__ wproj,
                       const float* __restrict__ wfc1, const float* __restrict__ wfc2,
                       ushortT* __restrict__ wqkvp, float* __restrict__ bqkvp,
                       ushortT* __restrict__ wprojb, ushortT* __restrict__ wfc1b,
                       ushortT* __restrict__ wfc2b, float* __restrict__ bm)
{
  int i = blockIdx.x * 256 + threadIdx.x;
  if (i < 110592){ // w_qkv permuted: out row rp = s*192 + h*32 + d  <- in row d*18+h*3+s
    int rp = i / 192, c = i % 192;
    int s = rp / 192, rem = rp % 192, hh = rem / 32, d = rem % 32;
    int rin = d*18 + hh*3 + s;
    float v = wqkv[rin*192 + c];
    if (s == 0) v *= SCALE_Q;
    wqkvp[i] = f2bf(v);
    return;
  }
  i -= 110592;
  if (i < 576){
    int rp = i;
    int s = rp / 192, rem = rp % 192, hh = rem / 32, d = rem % 32;
    int rin = d*18 + hh*3 + s;
    float v = bqkv[rin];
    if (s == 0) v *= SCALE_Q;
    bqkvp[i] = v;
    return;
  }
  i -= 576;
  if (i < 36864){ wprojb[i] = f2bf(wproj[i]); return; }
  i -= 36864;
  if (i < 147456){ wfc1b[i] = f2bf(wfc1[i]); return; }
  i -= 147456;
  if (i < 147456){ wfc2b[i] = f2bf(wfc2[i]); return; }
  i -= 147456;
  if (i < 921984){ // bm[w][h][i][j] = rel-pos-bias + shift-mask
    int j = i % 49; int t = i / 49; int ii = t % 49; t /= 49; int hh = t % 6; int w = t / 6;
    int r1 = ii/7, c1 = ii%7, r2 = j/7, c2 = j%7;
    int idx = (r1 - r2 + 6)*13 + (c1 - c2 + 6);
    float bias = rpb[idx*6 + hh];
    int wy = w >> 3, wx = w & 7;
    int hi = wy*7 + r1, wi = wx*7 + c1, hj = wy*7 + r2, wj = wx*7 + c2;
    int regi = 3*((hi<49)?0:((hi<53)?1:2)) + ((wi<49)?0:((wi<53)?1:2));
    int regj = 3*((hj<49)?0:((hj<53)?1:2)) + ((wj<49)?0:((wj<53)?1:2));
    bm[i] = bias + ((regi != regj) ? -100.0f : 0.0f);
  }
}

// ---------------- k_tr: NCHW f32 -> NHWC bf16 ----------------
__global__ void k_tr(const float* __restrict__ x, ushortT* __restrict__ xsb)
{
  __shared__ float tile[192*57];
  int bh = blockIdx.x; int b = bh / 56, h = bh % 56;
  const float* src = x + (size_t)b*602112 + (size_t)h*56;
  for (int e = threadIdx.x; e < 192*56; e += 256){
    int c = e / 56, w = e % 56;
    tile[c*57 + w] = src[(size_t)c*3136 + w];
  }
  __syncthreads();
  ushortT* dst = xsb + (size_t)bh*56*192;
  for (int e = threadIdx.x; e < 56*192; e += 256){
    int w = e / 192, c = e % 192;
    dst[(size_t)w*192 + c] = f2bf(tile[c*57 + w]);
  }
}

// ---------------- k_attn: fused LN0+roll+window+QKV+attn+proj+residual+LN1 ----------------
// xsb: in = NHWC bf16 activations; out (same buffer, block-exclusive rows) = LN1 output bf16
__global__ __launch_bounds__(256,1) void k_attn(
  ushortT* __restrict__ xsb, const ushortT* __restrict__ wqkvp, const float* __restrict__ bqkvp,
  const ushortT* __restrict__ wprojb, const float* __restrict__ bproj,
  const float* __restrict__ g0, const float* __restrict__ be0,
  const float* __restrict__ g1, const float* __restrict__ be1,
  const float* __restrict__ bm, float* __restrict__ xs2)
{
  __shared__ ushortT xraw[49][200];   // shortcut (pre-LN window rows, bf16)
  __shared__ ushortT ln0[64][200];    // LN0 out; later proj-out
  __shared__ ushortT qs[64][200];     // q; later attn-out
  __shared__ ushortT ks[64][200];
  __shared__ ushortT vT[6][32][72];   // v transposed per head
  __shared__ ushortT Pw[4][16][72];   // per-wave softmax probs

  const int tid = threadIdx.x;
  const int lane = tid & 63, wv = tid >> 6;
  const int l15 = lane & 15, g = lane >> 4;
  const int wid = blockIdx.x;
  const int b = wid >> 6, wloc = wid & 63, wy = wloc >> 3, wx = wloc & 7;
  const int mbase = wv * 16;

  // Phase 1: gather rolled window into xraw (8-bf16 vector loads), zero LN pad rows
  for (int e = tid; e < 49*24; e += 256){
    int t = e / 24, c8 = e % 24;
    int r = t / 7, cc = t % 7;
    int hsrc = (wy*7 + r + 3) % 56;
    int wsrc = (wx*7 + cc + 3) % 56;
    uint4 v = *(const uint4*)(xsb + ((size_t)((b*56 + hsrc)*56 + wsrc))*192 + c8*8);
    *(uint4*)(&xraw[t][c8*8]) = v;
  }
  for (int e = tid; e < 15*192; e += 256){
    ln0[49 + e/192][e%192] = 0;
  }
  __syncthreads();

  // Phase 2: LN0 -> ln0 (bf16)
  for (int t = wv; t < 49; t += 4){
    float x0 = bf2f(xraw[t][lane]), x1 = bf2f(xraw[t][lane+64]), x2 = bf2f(xraw[t][lane+128]);
    float s = x0 + x1 + x2, sq = x0*x0 + x1*x1 + x2*x2;
    #pragma unroll
    for (int m = 1; m < 64; m <<= 1){ s += __shfl_xor(s, m, 64); sq += __shfl_xor(sq, m, 64); }
    float mu = s * (1.0f/192.0f);
    float var = sq * (1.0f/192.0f) - mu*mu;
    float rs = rsqrtf(var + 1e-5f);
    ln0[t][lane]     = f2bf((x0-mu)*rs*g0[lane]     + be0[lane]);
    ln0[t][lane+64]  = f2bf((x1-mu)*rs*g0[lane+64]  + be0[lane+64]);
    ln0[t][lane+128] = f2bf((x2-mu)*rs*g0[lane+128] + be0[lane+128]);
  }
  __syncthreads();

  // Phase 3: QKV GEMM — waves split the 36 output-col tiles, each holds all 64 A-rows
  {
    short8 a[4][6];
    #pragma unroll
    for (int mt = 0; mt < 4; mt++)
      #pragma unroll
      for (int kc = 0; kc < 6; kc++)
        a[mt][kc] = *(const short8*)(&ln0[mt*16 + l15][kc*32 + g*8]);
    for (int ntl = 0; ntl < 9; ntl++){
      int nt = wv*9 + ntl;
      int cp = nt*16 + l15;
      const ushortT* wp = wqkvp + (size_t)cp*192 + g*8;
      short8 bfr[6];
      #pragma unroll
      for (int kc = 0; kc < 6; kc++) bfr[kc] = *(const short8*)(wp + kc*32);
      float bias = bqkvp[cp];
      #pragma unroll
      for (int mt = 0; mt < 4; mt++){
        f32x4 acc = {0.f,0.f,0.f,0.f};
        #pragma unroll
        for (int kc = 0; kc < 6; kc++) acc = MFMA16(a[mt][kc], bfr[kc], acc);
        #pragma unroll
        for (int r = 0; r < 4; r++){
          int tok = mt*16 + g*4 + r;
          float v = acc[r] + bias;
          if (cp < 192)      qs[tok][cp] = f2bf(v);
          else if (cp < 384) ks[tok][cp-192] = f2bf(v);
          else { int c2 = cp - 384; vT[c2>>5][c2&31][tok] = f2bf(v); }
        }
      }
    }
  }
  __syncthreads();

  // Phase 4: per-head attention (wave-local 16 query rows)
  for (int h = 0; h < 6; h++){
    short8 aq = *(const short8*)(&qs[mbase + l15][h*32 + g*8]);
    f32x4 sreg[4];
    #pragma unroll
    for (int jt = 0; jt < 4; jt++){
      short8 bk = *(const short8*)(&ks[jt*16 + l15][h*32 + g*8]);
      f32x4 z = {0.f,0.f,0.f,0.f};
      sreg[jt] = MFMA16(aq, bk, z);
    }
    #pragma unroll
    for (int r = 0; r < 4; r++){
      int i = mbase + g*4 + r;
      const float* bmrow = bm + (((size_t)(wloc*6 + h)*49 + i)*49);
      float rv[4];
      #pragma unroll
      for (int jt = 0; jt < 4; jt++){
        int j = jt*16 + l15;
        float sv = sreg[jt][r];
        if (i < 49 && j < 49) sv += bmrow[j];
        else sv = -1e30f;
        rv[jt] = sv;
      }
      float mx = fmaxf(fmaxf(rv[0],rv[1]), fmaxf(rv[2],rv[3]));
      #pragma unroll
      for (int m = 1; m < 16; m <<= 1) mx = fmaxf(mx, __shfl_xor(mx, m, 64));
      float sum = 0.f;
      #pragma unroll
      for (int jt = 0; jt < 4; jt++){ rv[jt] = __expf(rv[jt] - mx); sum += rv[jt]; }
      #pragma unroll
      for (int m = 1; m < 16; m <<= 1) sum += __shfl_xor(sum, m, 64);
      float rden = 1.0f / sum;
      #pragma unroll
      for (int jt = 0; jt < 4; jt++)
        Pw[wv][g*4+r][jt*16 + l15] = f2bf(rv[jt] * rden);
    }
    #pragma unroll
    for (int nt2 = 0; nt2 < 2; nt2++){
      f32x4 oacc = {0.f,0.f,0.f,0.f};
      #pragma unroll
      for (int kk = 0; kk < 2; kk++){
        short8 ap = *(const short8*)(&Pw[wv][l15][kk*32 + g*8]);
        short8 bv = *(const short8*)(&vT[h][nt2*16 + l15][kk*32 + g*8]);
        oacc = MFMA16(ap, bv, oacc);
      }
      #pragma unroll
      for (int r = 0; r < 4; r++)
        qs[mbase + g*4 + r][h*32 + nt2*16 + l15] = f2bf(oacc[r]);
    }
  }
  __syncthreads();

  // Phase 5a: proj GEMM — waves split the 12 output-col tiles; proj-out -> ln0 (bf16)
  {
    short8 a2[4][6];
    #pragma unroll
    for (int mt = 0; mt < 4; mt++)
      #pragma unroll
      for (int kc = 0; kc < 6; kc++)
        a2[mt][kc] = *(const short8*)(&qs[mt*16 + l15][kc*32 + g*8]);
    #pragma unroll
    for (int ntl = 0; ntl < 3; ntl++){
      int nt = wv*3 + ntl;
      int cp = nt*16 + l15;
      const ushortT* wp = wprojb + (size_t)cp*192 + g*8;
      short8 bfr[6];
      #pragma unroll
      for (int kc = 0; kc < 6; kc++) bfr[kc] = *(const short8*)(wp + kc*32);
      #pragma unroll
      for (int mt = 0; mt < 4; mt++){
        f32x4 acc = {0.f,0.f,0.f,0.f};
        #pragma unroll
        for (int kc = 0; kc < 6; kc++) acc = MFMA16(a2[mt][kc], bfr[kc], acc);
        #pragma unroll
        for (int r = 0; r < 4; r++)
          ln0[mt*16 + g*4 + r][cp] = f2bf(acc[r]);
      }
    }
  }
  __syncthreads();

  // Phase 5b: residual + LN1 + global writes (full-wave rows)
  for (int t = wv; t < 49; t += 4){
    float v0 = bf2f(ln0[t][lane])     + bproj[lane]     + bf2f(xraw[t][lane]);
    float v1 = bf2f(ln0[t][lane+64])  + bproj[lane+64]  + bf2f(xraw[t][lane+64]);
    float v2 = bf2f(ln0[t][lane+128]) + bproj[lane+128] + bf2f(xraw[t][lane+128]);
    float s = v0 + v1 + v2, sq = v0*v0 + v1*v1 + v2*v2;
    #pragma unroll
    for (int m = 1; m < 64; m <<= 1){ s += __shfl_xor(s, m, 64); sq += __shfl_xor(sq, m, 64); }
    float mu = s * (1.0f/192.0f);
    float var = sq * (1.0f/192.0f) - mu*mu;
    float rs = rsqrtf(var + 1e-5f);
    int rr = t / 7, cc = t % 7;
    int hdst = (wy*7 + rr + 3) % 56, wdst = (wx*7 + cc + 3) % 56;
    size_t gtok = ((size_t)(b*56 + hdst)*56 + wdst)*192;
    xs2[gtok + lane]     = v0;
    xs2[gtok + lane+64]  = v1;
    xs2[gtok + lane+128] = v2;
    xsb[gtok + lane]     = f2bf((v0-mu)*rs*g1[lane]     + be1[lane]);
    xsb[gtok + lane+64]  = f2bf((v1-mu)*rs*g1[lane+64]  + be1[lane+64]);
    xsb[gtok + lane+128] = f2bf((v2-mu)*rs*g1[lane+128] + be1[lane+128]);
  }
}

// ---------------- k_mlp: 256x192-tile GEMM; EPI 0 = GELU->bf16, EPI 1 = residual->NCHW f32 ----------------
template<int KV, int EPI>
__global__ __launch_bounds__(512,1) void k_mlp(const ushortT* __restrict__ A,
                                               const ushortT* __restrict__ Bw,
                                               const float* __restrict__ bias,
                                               ushortT* __restrict__ OutBf,
                                               const float* __restrict__ xs2,
                                               float* __restrict__ OutF,
                                               unsigned tokBase)
{
  __shared__ ushortT Abuf[256][32];
  __shared__ ushortT Bbuf[192][32];
  const int tid = threadIdx.x, lane = tid & 63, wv = tid >> 6;
  const int l15 = lane & 15, g = lane >> 4;
  const int wm = wv >> 1, wn = wv & 1;   // 4 x 2 wave grid; wave tile 64 x 96
  const size_t Mbase = (size_t)blockIdx.x * 256;
  const int Nbase = blockIdx.y * 192;

  f32x4 acc[4][6];
  #pragma unroll
  for (int it = 0; it < 4; it++)
    #pragma unroll
    for (int nt = 0; nt < 6; nt++) acc[it][nt] = (f32x4){0.f,0.f,0.f,0.f};

  for (int ksI = 0; ksI < KV/32; ksI++){
    #pragma unroll
    for (int cc2 = 0; cc2 < 2; cc2++){
      int chunk = tid + cc2*512; int row = chunk >> 2, part = chunk & 3;
      *(uint4*)(&Abuf[row][part*8]) =
        *(const uint4*)(A + (Mbase + row)*KV + ksI*32 + part*8);
    }
    {
      int row = tid >> 2, part = tid & 3;
      *(uint4*)(&Bbuf[row][part*8]) =
        *(const uint4*)(Bw + (size_t)(Nbase + row)*KV + ksI*32 + part*8);
    }
    if (tid < 256){
      int chunk = 512 + tid; int row = chunk >> 2, part = chunk & 3;
      *(uint4*)(&Bbuf[row][part*8]) =
        *(const uint4*)(Bw + (size_t)(Nbase + row)*KV + ksI*32 + part*8);
    }
    __syncthreads();
    short8 af[4], bf[6];
    #pragma unroll
    for (int it = 0; it < 4; it++)
      af[it] = *(const short8*)(&Abuf[wm*64 + it*16 + l15][g*8]);
    #pragma unroll
    for (int nt = 0; nt < 6; nt++)
      bf[nt] = *(const short8*)(&Bbuf[wn*96 + nt*16 + l15][g*8]);
    #pragma unroll
    for (int it = 0; it < 4; it++)
      #pragma unroll
      for (int nt = 0; nt < 6; nt++)
        acc[it][nt] = MFMA16(af[it], bf[nt], acc[it][nt]);
    __syncthreads();
  }

  #pragma unroll
  for (int nt = 0; nt < 6; nt++){
    int cpl = wn*96 + nt*16 + l15;
    int cpg = Nbase + cpl;
    float bs = bias[cpg];
    #pragma unroll
    for (int it = 0; it < 4; it++){
      #pragma unroll
      for (int r = 0; r < 4; r++){
        size_t tok = Mbase + wm*64 + it*16 + g*4 + r;   // local within chunk
        float v = acc[it][nt][r] + bs;
        if (EPI == 0){
          float ge = 0.5f * v * (1.0f + erff(v * 0.70710678118654752f));
          OutBf[tok*768 + cpg] = f2bf(ge);
        } else {
          v += xs2[tok*192 + cpg];
          unsigned t32 = tokBase + (unsigned)tok;       // global token
          unsigned bb = t32 / 3136u; unsigned rem = t32 % 3136u;
          OutF[(size_t)bb*602112 + (size_t)cpg*3136 + rem] = v;
        }
      }
    }
  }
}

// ---------------- launch ----------------
extern "C" void kernel_launch(void* const* d_in, const int* in_sizes, int n_in,
                              void* d_out, int out_size, void* d_ws, size_t ws_size,
                              hipStream_t stream)
{
  const float* x      = (const float*)d_in[0];
  const float* rpb    = (const float*)d_in[1];
  const float* w_qkv  = (const float*)d_in[2];
  const float* b_qkv  = (const float*)d_in[3];
  const float* w_proj = (const float*)d_in[4];
  const float* b_proj = (const float*)d_in[5];
  const float* g0     = (const float*)d_in[6];
  const float* be0    = (const float*)d_in[7];
  const float* g1     = (const float*)d_in[8];
  const float* be1    = (const float*)d_in[9];
  const float* w_fc1  = (const float*)d_in[10];
  const float* b_fc1  = (const float*)d_in[11];
  const float* w_fc2  = (const float*)d_in[12];
  const float* b_fc2  = (const float*)d_in[13];
  float* out = (float*)d_out;
  char* ws = (char*)d_ws;

  // Fixed workspace layout (ends at 235,785,984 bytes ~= 236 MB)
  ushortT* xsb    = (ushortT*)(ws);                    // 77,070,336 B (NHWC bf16; later LN1-out)
  float*   xs2    = (float*)(ws + 77070336);           // 154,140,672 B (residual f32)
  ushortT* wqkvp  = (ushortT*)(ws + 231211008);        // 221,184 B
  float*   bqkvp  = (float*)(ws + 231432192);          // 2,304 B
  ushortT* wprojb = (ushortT*)(ws + 231434496);        // 73,728 B
  ushortT* wfc1b  = (ushortT*)(ws + 231508224);        // 294,912 B
  ushortT* wfc2b  = (ushortT*)(ws + 231803136);        // 294,912 B
  float*   bm     = (float*)(ws + 232098048);          // 3,687,936 B
  ushortT* hmid   = (ushortT*)(ws + 235785984);        // rest: GELU intermediate chunks

  // Adaptive M-chunking of the MLP based on available scratch for hmid (768 bf16/row).
  long long avail = (ws_size > 235785984ull) ? (long long)(ws_size - 235785984ull) : 0;
  long long rows = (avail / 1536) / 256 * 256;
  if (rows < 256) rows = 256;
  if (rows > 200704) rows = 200704;

  k_prep<<<5332, 256, 0, stream>>>(rpb, w_qkv, b_qkv, w_proj, w_fc1, w_fc2,
                                   wqkvp, bqkvp, wprojb, wfc1b, wfc2b, bm);
  k_tr<<<3584, 256, 0, stream>>>(x, xsb);
  k_attn<<<4096, 256, 0, stream>>>(xsb, wqkvp, bqkvp, wprojb, b_proj,
                                   g0, be0, g1, be1, bm, xs2);
  for (long long s0 = 0; s0 < 200704; s0 += rows){
    long long r = 200704 - s0; if (r > rows) r = rows;
    unsigned nbx = (unsigned)(r / 256);
    k_mlp<192,0><<<dim3(nbx,4), 512, 0, stream>>>(xsb + s0*192, wfc1b, b_fc1,
                                                  hmid, nullptr, nullptr, 0u);
    k_mlp<768,1><<<dim3(nbx,1), 512, 0, stream>>>(hmid, wfc2b, b_fc2,
                                                  nullptr, xs2 + s0*192, out, (unsigned)s0);
  }
}

// Round 3
// 1168.279 us; speedup vs baseline: 1.2080x; 1.2080x over previous
//
#include <hip/hip_runtime.h>
#include <hip/hip_bf16.h>

typedef unsigned short ushortT;
typedef __attribute__((ext_vector_type(8))) short short8;
typedef __attribute__((ext_vector_type(4))) float f32x4;

#define MFMA16(a,b,c) __builtin_amdgcn_mfma_f32_16x16x32_bf16(a,b,c,0,0,0)

__device__ __forceinline__ ushortT f2bf(float f){
  union {float f; unsigned u;} v; v.f = f;
  unsigned r = v.u + 0x7FFFu + ((v.u >> 16) & 1u);
  return (ushortT)(r >> 16);
}
__device__ __forceinline__ float bf2f(ushortT u){
  union {unsigned u; float f;} v; v.u = ((unsigned)u) << 16; return v.f;
}

// B=64, C=192, IMG=56, WS=7, SS=3, NH=6, DH=32, N=49, nWs=8, windows=4096, T=200704
#define SCALE_Q 0.17677669529663687f

// ---------------- k_prep: weight permute/convert + bias/mask table ----------------
__global__ void k_prep(const float* __restrict__ rpb, const float* __restrict__ wqkv,
                       const float* __restrict__ bqkv, const float* __restrict__ wproj,
                       const float* __restrict__ wfc1, const float* __restrict__ wfc2,
                       ushortT* __restrict__ wqkvp, float* __restrict__ bqkvp,
                       ushortT* __restrict__ wprojb, ushortT* __restrict__ wfc1b,
                       ushortT* __restrict__ wfc2b, float* __restrict__ bm)
{
  int i = blockIdx.x * 256 + threadIdx.x;
  if (i < 110592){ // w_qkv permuted: out row rp = s*192 + h*32 + d  <- in row d*18+h*3+s
    int rp = i / 192, c = i % 192;
    int s = rp / 192, rem = rp % 192, hh = rem / 32, d = rem % 32;
    int rin = d*18 + hh*3 + s;
    float v = wqkv[rin*192 + c];
    if (s == 0) v *= SCALE_Q;
    wqkvp[i] = f2bf(v);
    return;
  }
  i -= 110592;
  if (i < 576){
    int rp = i;
    int s = rp / 192, rem = rp % 192, hh = rem / 32, d = rem % 32;
    int rin = d*18 + hh*3 + s;
    float v = bqkv[rin];
    if (s == 0) v *= SCALE_Q;
    bqkvp[i] = v;
    return;
  }
  i -= 576;
  if (i < 36864){ wprojb[i] = f2bf(wproj[i]); return; }
  i -= 36864;
  if (i < 147456){ wfc1b[i] = f2bf(wfc1[i]); return; }
  i -= 147456;
  if (i < 147456){ wfc2b[i] = f2bf(wfc2[i]); return; }
  i -= 147456;
  if (i < 921984){ // bm[w][h][i][j] = rel-pos-bias + shift-mask
    int j = i % 49; int t = i / 49; int ii = t % 49; t /= 49; int hh = t % 6; int w = t / 6;
    int r1 = ii/7, c1 = ii%7, r2 = j/7, c2 = j%7;
    int idx = (r1 - r2 + 6)*13 + (c1 - c2 + 6);
    float bias = rpb[idx*6 + hh];
    int wy = w >> 3, wx = w & 7;
    int hi = wy*7 + r1, wi = wx*7 + c1, hj = wy*7 + r2, wj = wx*7 + c2;
    int regi = 3*((hi<49)?0:((hi<53)?1:2)) + ((wi<49)?0:((wi<53)?1:2));
    int regj = 3*((hj<49)?0:((hj<53)?1:2)) + ((wj<49)?0:((wj<53)?1:2));
    bm[i] = bias + ((regi != regj) ? -100.0f : 0.0f);
  }
}

// ---------------- k_tr: NCHW f32 -> NHWC bf16 ----------------
__global__ void k_tr(const float* __restrict__ x, ushortT* __restrict__ xsb)
{
  __shared__ float tile[192*57];
  int bh = blockIdx.x; int b = bh / 56, h = bh % 56;
  const float* src = x + (size_t)b*602112 + (size_t)h*56;
  for (int e = threadIdx.x; e < 192*56; e += 256){
    int c = e / 56, w = e % 56;
    tile[c*57 + w] = src[(size_t)c*3136 + w];
  }
  __syncthreads();
  ushortT* dst = xsb + (size_t)bh*56*192;
  for (int e = threadIdx.x; e < 56*192; e += 256){
    int w = e / 192, c = e % 192;
    dst[(size_t)w*192 + c] = f2bf(tile[c*57 + w]);
  }
}

// ---------------- k_attn: fused LN0+roll+window+QKV+attn+proj+residual+LN1 ----------------
// LDS = 76,064 B -> 2 blocks/CU. Token-row buffers are 49 rows; MFMA fragment
// row indices clamp to 48 (dup rows masked downstream), stores guarded tok<49.
__global__ __launch_bounds__(256,2) void k_attn(
  ushortT* __restrict__ xsb, const ushortT* __restrict__ wqkvp, const float* __restrict__ bqkvp,
  const ushortT* __restrict__ wprojb, const float* __restrict__ bproj,
  const float* __restrict__ g0, const float* __restrict__ be0,
  const float* __restrict__ g1, const float* __restrict__ be1,
  const float* __restrict__ bm, float* __restrict__ xs2)
{
  __shared__ ushortT ln0[49][200];    // LN0 out -> Q -> attn-out -> proj-out
  __shared__ ushortT ks[49][200];
  __shared__ ushortT vT[6][32][72];   // v transposed per head (cols=tokens 0..63)
  __shared__ ushortT Pw[4][16][72];   // per-wave softmax probs

  const int tid = threadIdx.x;
  const int lane = tid & 63, wv = tid >> 6;
  const int l15 = lane & 15, g = lane >> 4;
  const int wid = blockIdx.x;
  const int b = wid >> 6, wloc = wid & 63, wy = wloc >> 3, wx = wloc & 7;
  const int mbase = wv * 16;

  // Phase 2: LN0 directly from global (rolled window rows) -> ln0 (bf16)
  for (int t = wv; t < 49; t += 4){
    int r = t / 7, cc = t % 7;
    int hsrc = (wy*7 + r + 3) % 56;
    int wsrc = (wx*7 + cc + 3) % 56;
    const ushortT* px = xsb + ((size_t)((b*56 + hsrc)*56 + wsrc))*192;
    float x0 = bf2f(px[lane]), x1 = bf2f(px[lane+64]), x2 = bf2f(px[lane+128]);
    float s = x0 + x1 + x2, sq = x0*x0 + x1*x1 + x2*x2;
    #pragma unroll
    for (int m = 1; m < 64; m <<= 1){ s += __shfl_xor(s, m, 64); sq += __shfl_xor(sq, m, 64); }
    float mu = s * (1.0f/192.0f);
    float var = sq * (1.0f/192.0f) - mu*mu;
    float rs = rsqrtf(var + 1e-5f);
    ln0[t][lane]     = f2bf((x0-mu)*rs*g0[lane]     + be0[lane]);
    ln0[t][lane+64]  = f2bf((x1-mu)*rs*g0[lane+64]  + be0[lane+64]);
    ln0[t][lane+128] = f2bf((x2-mu)*rs*g0[lane+128] + be0[lane+128]);
  }
  __syncthreads();

  // Phase 3: QKV GEMM — waves split the 36 output-col tiles, all 64 A-rows in regs
  {
    short8 a[4][6];
    #pragma unroll
    for (int mt = 0; mt < 4; mt++){
      int ra = mt*16 + l15; if (ra > 48) ra = 48;   // clamp (dup rows masked later)
      #pragma unroll
      for (int kc = 0; kc < 6; kc++)
        a[mt][kc] = *(const short8*)(&ln0[ra][kc*32 + g*8]);
    }
    __syncthreads();   // all A-reads done before Q overwrites ln0
    for (int ntl = 0; ntl < 9; ntl++){
      int nt = wv*9 + ntl;
      int cp = nt*16 + l15;
      const ushortT* wp = wqkvp + (size_t)cp*192 + g*8;
      short8 bfr[6];
      #pragma unroll
      for (int kc = 0; kc < 6; kc++) bfr[kc] = *(const short8*)(wp + kc*32);
      float bias = bqkvp[cp];
      #pragma unroll
      for (int mt = 0; mt < 4; mt++){
        f32x4 acc = {0.f,0.f,0.f,0.f};
        #pragma unroll
        for (int kc = 0; kc < 6; kc++) acc = MFMA16(a[mt][kc], bfr[kc], acc);
        #pragma unroll
        for (int r = 0; r < 4; r++){
          int tok = mt*16 + g*4 + r;
          float v = acc[r] + bias;
          if (cp < 192)      { if (tok < 49) ln0[tok][cp] = f2bf(v); }
          else if (cp < 384) { if (tok < 49) ks[tok][cp-192] = f2bf(v); }
          else { int c2 = cp - 384; vT[c2>>5][c2&31][tok] = f2bf(v); }
        }
      }
    }
  }
  __syncthreads();

  // Phase 4: per-head attention (wave-local 16 query rows; row indices clamped)
  const int rq = (mbase + l15 > 48) ? 48 : (mbase + l15);
  for (int h = 0; h < 6; h++){
    short8 aq = *(const short8*)(&ln0[rq][h*32 + g*8]);
    f32x4 sreg[4];
    #pragma unroll
    for (int jt = 0; jt < 4; jt++){
      int rk = jt*16 + l15; if (rk > 48) rk = 48;
      short8 bk = *(const short8*)(&ks[rk][h*32 + g*8]);
      f32x4 z = {0.f,0.f,0.f,0.f};
      sreg[jt] = MFMA16(aq, bk, z);
    }
    #pragma unroll
    for (int r = 0; r < 4; r++){
      int i = mbase + g*4 + r;
      const float* bmrow = bm + (((size_t)(wloc*6 + h)*49 + i)*49);
      float rv[4];
      #pragma unroll
      for (int jt = 0; jt < 4; jt++){
        int j = jt*16 + l15;
        float sv = sreg[jt][r];
        if (i < 49 && j < 49) sv += bmrow[j];
        else sv = -1e30f;
        rv[jt] = sv;
      }
      float mx = fmaxf(fmaxf(rv[0],rv[1]), fmaxf(rv[2],rv[3]));
      #pragma unroll
      for (int m = 1; m < 16; m <<= 1) mx = fmaxf(mx, __shfl_xor(mx, m, 64));
      float sum = 0.f;
      #pragma unroll
      for (int jt = 0; jt < 4; jt++){ rv[jt] = __expf(rv[jt] - mx); sum += rv[jt]; }
      #pragma unroll
      for (int m = 1; m < 16; m <<= 1) sum += __shfl_xor(sum, m, 64);
      float rden = 1.0f / sum;
      #pragma unroll
      for (int jt = 0; jt < 4; jt++)
        Pw[wv][g*4+r][jt*16 + l15] = f2bf(rv[jt] * rden);
    }
    #pragma unroll
    for (int nt2 = 0; nt2 < 2; nt2++){
      f32x4 oacc = {0.f,0.f,0.f,0.f};
      #pragma unroll
      for (int kk = 0; kk < 2; kk++){
        short8 ap = *(const short8*)(&Pw[wv][l15][kk*32 + g*8]);
        short8 bv = *(const short8*)(&vT[h][nt2*16 + l15][kk*32 + g*8]);
        oacc = MFMA16(ap, bv, oacc);
      }
      #pragma unroll
      for (int r = 0; r < 4; r++){
        int tok = mbase + g*4 + r;
        if (tok < 49) ln0[tok][h*32 + nt2*16 + l15] = f2bf(oacc[r]);
      }
    }
  }
  __syncthreads();

  // Phase 5a: proj GEMM — waves split the 12 output-col tiles; proj-out -> ln0
  {
    short8 a2[4][6];
    #pragma unroll
    for (int mt = 0; mt < 4; mt++){
      int ra = mt*16 + l15; if (ra > 48) ra = 48;
      #pragma unroll
      for (int kc = 0; kc < 6; kc++)
        a2[mt][kc] = *(const short8*)(&ln0[ra][kc*32 + g*8]);
    }
    __syncthreads();   // all attn-out reads done before proj-out overwrites ln0
    #pragma unroll
    for (int ntl = 0; ntl < 3; ntl++){
      int nt = wv*3 + ntl;
      int cp = nt*16 + l15;
      const ushortT* wp = wprojb + (size_t)cp*192 + g*8;
      short8 bfr[6];
      #pragma unroll
      for (int kc = 0; kc < 6; kc++) bfr[kc] = *(const short8*)(wp + kc*32);
      #pragma unroll
      for (int mt = 0; mt < 4; mt++){
        f32x4 acc = {0.f,0.f,0.f,0.f};
        #pragma unroll
        for (int kc = 0; kc < 6; kc++) acc = MFMA16(a2[mt][kc], bfr[kc], acc);
        #pragma unroll
        for (int r = 0; r < 4; r++){
          int tok = mt*16 + g*4 + r;
          if (tok < 49) ln0[tok][cp] = f2bf(acc[r]);
        }
      }
    }
  }
  __syncthreads();

  // Phase 5b: residual (re-read global) + LN1 + global writes
  for (int t = wv; t < 49; t += 4){
    int rr = t / 7, cc = t % 7;
    int hdst = (wy*7 + rr + 3) % 56, wdst = (wx*7 + cc + 3) % 56;
    size_t gtok = ((size_t)(b*56 + hdst)*56 + wdst)*192;
    float v0 = bf2f(ln0[t][lane])     + bproj[lane]     + bf2f(xsb[gtok + lane]);
    float v1 = bf2f(ln0[t][lane+64])  + bproj[lane+64]  + bf2f(xsb[gtok + lane+64]);
    float v2 = bf2f(ln0[t][lane+128]) + bproj[lane+128] + bf2f(xsb[gtok + lane+128]);
    float s = v0 + v1 + v2, sq = v0*v0 + v1*v1 + v2*v2;
    #pragma unroll
    for (int m = 1; m < 64; m <<= 1){ s += __shfl_xor(s, m, 64); sq += __shfl_xor(sq, m, 64); }
    float mu = s * (1.0f/192.0f);
    float var = sq * (1.0f/192.0f) - mu*mu;
    float rs = rsqrtf(var + 1e-5f);
    xs2[gtok + lane]     = v0;
    xs2[gtok + lane+64]  = v1;
    xs2[gtok + lane+128] = v2;
    xsb[gtok + lane]     = f2bf((v0-mu)*rs*g1[lane]     + be1[lane]);
    xsb[gtok + lane+64]  = f2bf((v1-mu)*rs*g1[lane+64]  + be1[lane+64]);
    xsb[gtok + lane+128] = f2bf((v2-mu)*rs*g1[lane+128] + be1[lane+128]);
  }
}

// ---------------- k_mlp_fused: fc1 + GELU + fc2 + bias + residual -> NCHW f32 ----------------
// Wave-private 32-row pipeline; A-fragments direct from global; zero barriers.
__global__ __launch_bounds__(256,2) void k_mlp_fused(
  const ushortT* __restrict__ A,      // LN1 out, bf16 [200704][192]
  const ushortT* __restrict__ w1,     // bf16 [768][192]
  const float* __restrict__ b1,
  const ushortT* __restrict__ w2,     // bf16 [192][768]
  const float* __restrict__ b2,
  const float* __restrict__ xs2,      // residual f32 [200704][192]
  float* __restrict__ out)            // NCHW f32
{
  __shared__ ushortT Hbuf[128][104];  // 26,624 B; wave-private 32-row slices
  const int tid = threadIdx.x, lane = tid & 63, wv = tid >> 6;
  const int l15 = lane & 15, g = lane >> 4;
  const size_t Mbase = (size_t)blockIdx.x * 128;
  const int rowb = wv * 32;

  // A fragments straight from global (g-groups cover contiguous 64B lines)
  short8 a[2][6];
  #pragma unroll
  for (int mt = 0; mt < 2; mt++){
    size_t row = Mbase + rowb + mt*16 + l15;
    #pragma unroll
    for (int kc = 0; kc < 6; kc++)
      a[mt][kc] = *(const short8*)(A + row*192 + kc*32 + g*8);
  }

  f32x4 acc2[2][12];
  #pragma unroll
  for (int mt = 0; mt < 2; mt++)
    #pragma unroll
    for (int nt = 0; nt < 12; nt++) acc2[mt][nt] = (f32x4){0.f,0.f,0.f,0.f};

  for (int hb = 0; hb < 8; hb++){   // hidden blocks of 96
    const int hbase = hb * 96;
    // fc1 + GELU -> Hbuf (wave's own 32 rows)
    #pragma unroll
    for (int nt = 0; nt < 6; nt++){
      int hc = hbase + nt*16 + l15;
      const ushortT* wp = w1 + (size_t)hc*192 + g*8;
      short8 bfr[6];
      #pragma unroll
      for (int kc = 0; kc < 6; kc++) bfr[kc] = *(const short8*)(wp + kc*32);
      float bias = b1[hc];
      #pragma unroll
      for (int mt = 0; mt < 2; mt++){
        f32x4 acc = {0.f,0.f,0.f,0.f};
        #pragma unroll
        for (int kc = 0; kc < 6; kc++) acc = MFMA16(a[mt][kc], bfr[kc], acc);
        #pragma unroll
        for (int r = 0; r < 4; r++){
          float v = acc[r] + bias;
          float ge = 0.5f * v * (1.0f + erff(v * 0.70710678118654752f));
          Hbuf[rowb + mt*16 + g*4 + r][nt*16 + l15] = f2bf(ge);
        }
      }
    }
    // fc2 partial: K=96 (3 k-chunks); same wave reads its own Hbuf rows
    short8 h2f[2][3];
    #pragma unroll
    for (int mt = 0; mt < 2; mt++)
      #pragma unroll
      for (int kk = 0; kk < 3; kk++)
        h2f[mt][kk] = *(const short8*)(&Hbuf[rowb + mt*16 + l15][kk*32 + g*8]);
    #pragma unroll
    for (int nt = 0; nt < 12; nt++){
      int c = nt*16 + l15;
      const ushortT* wp = w2 + (size_t)c*768 + hbase + g*8;
      short8 bfr[3];
      #pragma unroll
      for (int kk = 0; kk < 3; kk++) bfr[kk] = *(const short8*)(wp + kk*32);
      #pragma unroll
      for (int mt = 0; mt < 2; mt++)
        #pragma unroll
        for (int kk = 0; kk < 3; kk++)
          acc2[mt][nt] = MFMA16(h2f[mt][kk], bfr[kk], acc2[mt][nt]);
    }
  }

  // Epilogue: + b2 + residual -> NCHW
  #pragma unroll
  for (int nt = 0; nt < 12; nt++){
    int c = nt*16 + l15;
    float bs = b2[c];
    #pragma unroll
    for (int mt = 0; mt < 2; mt++){
      #pragma unroll
      for (int r = 0; r < 4; r++){
        size_t tok = Mbase + rowb + mt*16 + g*4 + r;
        float v = acc2[mt][nt][r] + bs + xs2[tok*192 + c];
        unsigned t32 = (unsigned)tok;
        unsigned bb = t32 / 3136u, rem = t32 % 3136u;
        out[(size_t)bb*602112 + (size_t)c*3136 + rem] = v;
      }
    }
  }
}

// ---------------- launch ----------------
extern "C" void kernel_launch(void* const* d_in, const int* in_sizes, int n_in,
                              void* d_out, int out_size, void* d_ws, size_t ws_size,
                              hipStream_t stream)
{
  const float* x      = (const float*)d_in[0];
  const float* rpb    = (const float*)d_in[1];
  const float* w_qkv  = (const float*)d_in[2];
  const float* b_qkv  = (const float*)d_in[3];
  const float* w_proj = (const float*)d_in[4];
  const float* b_proj = (const float*)d_in[5];
  const float* g0     = (const float*)d_in[6];
  const float* be0    = (const float*)d_in[7];
  const float* g1     = (const float*)d_in[8];
  const float* be1    = (const float*)d_in[9];
  const float* w_fc1  = (const float*)d_in[10];
  const float* b_fc1  = (const float*)d_in[11];
  const float* w_fc2  = (const float*)d_in[12];
  const float* b_fc2  = (const float*)d_in[13];
  float* out = (float*)d_out;
  char* ws = (char*)d_ws;

  // Workspace layout (ends at ~236 MB)
  ushortT* xsb    = (ushortT*)(ws);                    // 77,070,336 B (NHWC bf16; later LN1-out)
  float*   xs2    = (float*)(ws + 77070336);           // 154,140,672 B (residual f32)
  ushortT* wqkvp  = (ushortT*)(ws + 231211008);        // 221,184 B
  float*   bqkvp  = (float*)(ws + 231432192);          // 2,304 B
  ushortT* wprojb = (ushortT*)(ws + 231434496);        // 73,728 B
  ushortT* wfc1b  = (ushortT*)(ws + 231508224);        // 294,912 B
  ushortT* wfc2b  = (ushortT*)(ws + 231803136);        // 294,912 B
  float*   bm     = (float*)(ws + 232098048);          // 3,687,936 B

  k_prep<<<5332, 256, 0, stream>>>(rpb, w_qkv, b_qkv, w_proj, w_fc1, w_fc2,
                                   wqkvp, bqkvp, wprojb, wfc1b, wfc2b, bm);
  k_tr<<<3584, 256, 0, stream>>>(x, xsb);
  k_attn<<<4096, 256, 0, stream>>>(xsb, wqkvp, bqkvp, wprojb, b_proj,
                                   g0, be0, g1, be1, bm, xs2);
  k_mlp_fused<<<1568, 256, 0, stream>>>(xsb, wfc1b, b_fc1, wfc2b, b_fc2, xs2, out);
}